// Round 8
// baseline (309.403 us; speedup 1.0000x reference)
//
#include <hip/hip_runtime.h>
#include <hip/hip_fp16.h>
#include <math.h>

#define N_NODES 50000
#define NE      800000
#define INC     128
#define F1      128     // HEADS*HID
#define HEADS   8
#define HID     16
#define OUTC    16
#define NEG     0.2f
#define NBKT    196      // (N_NODES+255)>>8
#define NPART   256      // partition blocks

union H4 { ushort4 u; __half h[4]; };
union H8 { uint4 u; __half h[8]; };

typedef _Float16 f16x8 __attribute__((ext_vector_type(8)));
typedef float    f32x4 __attribute__((ext_vector_type(4)));

// ============ CSR build: two-level counting sort (locality-friendly) ========
__global__ __launch_bounds__(256) void part_hist(const int* __restrict__ ei,
                                                 int* __restrict__ cnt) {
    __shared__ int h[NBKT];
    int tid = threadIdx.x;
    for (int i = tid; i < NBKT; i += 256) h[i] = 0;
    __syncthreads();
    for (int e = blockIdx.x * 256 + tid; e < NE; e += NPART * 256)
        atomicAdd(&h[ei[NE + e] >> 8], 1);
    __syncthreads();
    for (int i = tid; i < NBKT; i += 256) cnt[i * NPART + blockIdx.x] = h[i];
}

__global__ __launch_bounds__(1024) void scan50k(int* __restrict__ cnt) {
    __shared__ int part[1024];
    const int TOT = NBKT * NPART;
    const int PER = (TOT + 1023) / 1024;      // 49
    int tid = threadIdx.x;
    int base = tid * PER;
    int s = 0;
    for (int i = 0; i < PER; ++i) {
        int idx = base + i;
        if (idx < TOT) s += cnt[idx];
    }
    part[tid] = s; __syncthreads();
    for (int off = 1; off < 1024; off <<= 1) {
        int t = (tid >= off) ? part[tid - off] : 0;
        __syncthreads();
        part[tid] += t;
        __syncthreads();
    }
    int run = part[tid] - s;
    for (int i = 0; i < PER; ++i) {
        int idx = base + i;
        if (idx < TOT) { int v = cnt[idx]; cnt[idx] = run; run += v; }
    }
}

__global__ __launch_bounds__(256) void part_scatter(const int* __restrict__ ei,
                                                    const int* __restrict__ cnt,
                                                    int2* __restrict__ tmp) {
    __shared__ int cur[NBKT];
    int tid = threadIdx.x;
    for (int i = tid; i < NBKT; i += 256) cur[i] = cnt[i * NPART + blockIdx.x];
    __syncthreads();
    for (int e = blockIdx.x * 256 + tid; e < NE; e += NPART * 256) {
        int s = ei[e], d = ei[NE + e];
        int p = atomicAdd(&cur[d >> 8], 1);
        tmp[p] = make_int2(s, d);
    }
}

__global__ __launch_bounds__(256) void bucket_sort(const int2* __restrict__ tmp,
                                                   const int* __restrict__ cnt,
                                                   int* __restrict__ rowstart,
                                                   int* __restrict__ csr) {
    __shared__ int h[256];
    int b = blockIdx.x, tid = threadIdx.x;
    int base = cnt[b * NPART];
    int end  = (b == NBKT - 1) ? NE : cnt[(b + 1) * NPART];
    h[tid] = 0; __syncthreads();
    for (int i = base + tid; i < end; i += 256)
        atomicAdd(&h[tmp[i].y & 255], 1);
    __syncthreads();
    int v = h[tid];
    for (int off = 1; off < 256; off <<= 1) {
        int t = (tid >= off) ? h[tid - off] : 0;
        __syncthreads();
        h[tid] += t;
        __syncthreads();
    }
    int excl = h[tid] - v;
    int n = (b << 8) + tid;
    if (n <= N_NODES) rowstart[n] = base + excl;
    __syncthreads();
    h[tid] = excl;
    __syncthreads();
    for (int i = base + tid; i < end; i += 256) {
        int2 e = tmp[i];
        int p = base + atomicAdd(&h[e.y & 255], 1);
        csr[p] = e.x;
    }
}

// ---------------- Layer 1: MFMA GEMM (x @ W1), fp16 in, f32 acc ------------
__global__ __launch_bounds__(256) void node1_kernel(
    const float* __restrict__ x, const float* __restrict__ W1,
    const float* __restrict__ a_src, const float* __restrict__ a_dst,
    __half* __restrict__ hfeat, float* __restrict__ als, float* __restrict__ ald)
{
    __shared__ _Float16 Xh[64 * 136];    // 17.4 KB
    __shared__ _Float16 Wt[128 * 136];   // 34.8 KB
    int tid = threadIdx.x;
    int n0 = blockIdx.x * 64;

    for (int idx = tid; idx < INC * F1 / 4; idx += 256) {
        int k = idx >> 5, n4 = (idx & 31) * 4;
        float4 w = ((const float4*)W1)[idx];
        Wt[(n4 + 0) * 136 + k] = (_Float16)w.x;
        Wt[(n4 + 1) * 136 + k] = (_Float16)w.y;
        Wt[(n4 + 2) * 136 + k] = (_Float16)w.z;
        Wt[(n4 + 3) * 136 + k] = (_Float16)w.w;
    }
    for (int idx = tid; idx < 64 * 32; idx += 256) {
        int m = idx >> 5, f4 = idx & 31;
        int n = n0 + m;
        float4 v = (n < N_NODES) ? ((const float4*)(x + (size_t)n * INC))[f4]
                                 : make_float4(0.f, 0.f, 0.f, 0.f);
        union { unsigned long long u; _Float16 h[4]; } p;
        p.h[0] = (_Float16)v.x; p.h[1] = (_Float16)v.y;
        p.h[2] = (_Float16)v.z; p.h[3] = (_Float16)v.w;
        *(unsigned long long*)(&Xh[m * 136 + f4 * 4]) = p.u;
    }
    __syncthreads();

    int wave = tid >> 6, lane = tid & 63;
    int colL = lane & 15, q = lane >> 4;
    int nb = wave * 32;

    f32x4 acc[4][2];
    #pragma unroll
    for (int mt = 0; mt < 4; ++mt)
        #pragma unroll
        for (int nt = 0; nt < 2; ++nt)
            acc[mt][nt] = (f32x4){0.f, 0.f, 0.f, 0.f};

    #pragma unroll
    for (int kb = 0; kb < 4; ++kb) {
        int ko = kb * 32 + q * 8;
        f16x8 b0 = *(const f16x8*)(&Wt[(nb +  0 + colL) * 136 + ko]);
        f16x8 b1 = *(const f16x8*)(&Wt[(nb + 16 + colL) * 136 + ko]);
        #pragma unroll
        for (int mt = 0; mt < 4; ++mt) {
            f16x8 a = *(const f16x8*)(&Xh[(mt * 16 + colL) * 136 + ko]);
            acc[mt][0] = __builtin_amdgcn_mfma_f32_16x16x32_f16(a, b0, acc[mt][0], 0, 0, 0);
            acc[mt][1] = __builtin_amdgcn_mfma_f32_16x16x32_f16(a, b1, acc[mt][1], 0, 0, 0);
        }
    }

    #pragma unroll
    for (int nt = 0; nt < 2; ++nt) {
        int col = nb + nt * 16 + colL;
        int head = (nb >> 4) + nt;
        float asc = a_src[col], adc = a_dst[col];
        #pragma unroll
        for (int mt = 0; mt < 4; ++mt) {
            f32x4 d = acc[mt][nt];
            #pragma unroll
            for (int r = 0; r < 4; ++r) {
                int node = n0 + mt * 16 + q * 4 + r;
                float dv = d[r];
                if (node < N_NODES) hfeat[(size_t)node * F1 + col] = __float2half(dv);
                float ps = dv * asc, pd = dv * adc;
                ps += __shfl_xor(ps, 1, 16); pd += __shfl_xor(pd, 1, 16);
                ps += __shfl_xor(ps, 2, 16); pd += __shfl_xor(pd, 2, 16);
                ps += __shfl_xor(ps, 4, 16); pd += __shfl_xor(pd, 4, 16);
                ps += __shfl_xor(ps, 8, 16); pd += __shfl_xor(pd, 8, 16);
                if (colL == 0 && node < N_NODES) {
                    als[node * HEADS + head] = ps;
                    ald[node * HEADS + head] = pd;
                }
            }
        }
    }
}

// ====== Fused Layer-1 gather + softmax + ELU + Layer-2 GEMV + logits =======
// 16 nodes/block, 16 lanes/node, 8 fp16 feats/lane. Depth-2 row pipeline.
// Epilogue: o = elu(agg/sum + b1); h2 = o @ W2 (LDS-reduced); layer-2 logits.
__global__ __launch_bounds__(256) void agg1_node2_kernel(
    const int* __restrict__ rowstart, const int* __restrict__ csr,
    const __half* __restrict__ h1, const float* __restrict__ als,
    const float* __restrict__ ald, const float* __restrict__ b1,
    const float* __restrict__ W2, const float* __restrict__ a_s2,
    const float* __restrict__ a_d2,
    __half* __restrict__ h2, float* __restrict__ als2, float* __restrict__ ald2)
{
    __shared__ float W2l[F1 * OUTC];        // 8 KB
    __shared__ float scratch[16 * 272];     // 17.4 KB, 17-pad per lane-row
    int tid = threadIdx.x;
    for (int i = tid; i < F1 * OUTC; i += 256) W2l[i] = W2[i];

    int g = tid >> 4, lane = tid & 15;
    int n = blockIdx.x * 16 + g;
    int c = lane * 8;
    int head = lane >> 1;

    float aldn = ald[n * HEADS + head];
    float v0 = als[n * HEADS + head] + aldn;
    v0 = fmaxf(v0, NEG * v0);
    float w0 = __expf(v0);
    float sum = w0;
    float a[8];
    {
        H8 hs; hs.u = *(const uint4*)(h1 + (size_t)n * F1 + c);
        #pragma unroll
        for (int i = 0; i < 8; ++i) a[i] = w0 * __half2float(hs.h[i]);
    }
    int r0 = rowstart[n], r1 = rowstart[n + 1];

    // depth-2 pipeline: rows for k,k+1 in flight; csr prefetched 4 ahead
    int sP0 = (r0 + 2 < r1) ? csr[r0 + 2] : 0;
    int sP1 = (r0 + 3 < r1) ? csr[r0 + 3] : 0;
    float vb[2]; H8 hb[2];
    #pragma unroll
    for (int j = 0; j < 2; ++j) {
        vb[j] = 0.f; hb[j].u = make_uint4(0, 0, 0, 0);
        if (r0 + j < r1) {
            int s = csr[r0 + j];
            float t = als[s * HEADS + head] + aldn;
            vb[j] = fmaxf(t, NEG * t);
            hb[j].u = *(const uint4*)(h1 + (size_t)s * F1 + c);
        }
    }
    for (int k = r0; k < r1; ++k) {
        int i = (k - r0) & 1;
        float v = vb[i]; H8 hv = hb[i];
        int sn = sP0; sP0 = sP1; sP1 = (k + 4 < r1) ? csr[k + 4] : 0;
        if (k + 2 < r1) {
            float t = als[sn * HEADS + head] + aldn;
            vb[i] = fmaxf(t, NEG * t);
            hb[i].u = *(const uint4*)(h1 + (size_t)sn * F1 + c);
        }
        float w = __expf(v);
        sum += w;
        #pragma unroll
        for (int i8 = 0; i8 < 8; ++i8) a[i8] = fmaf(w, __half2float(hv.h[i8]), a[i8]);
    }

    // ELU'd layer-1 output features (fp32, no fp16 round-trip)
    float inv = 1.0f / sum;
    float e[8];
    #pragma unroll
    for (int i = 0; i < 8; ++i) {
        float o = a[i] * inv + b1[c + i];
        e[i] = o > 0.f ? o : (__expf(o) - 1.0f);
    }

    __syncthreads();   // W2l ready; scratch free

    // per-lane GEMV partials over its 8 k-slots
    float p[OUTC];
    #pragma unroll
    for (int j = 0; j < OUTC; ++j) p[j] = 0.f;
    #pragma unroll
    for (int i = 0; i < 8; ++i) {
        float ev = e[i];
        #pragma unroll
        for (int j = 0; j < OUTC; ++j)
            p[j] = fmaf(ev, W2l[(c + i) * OUTC + j], p[j]);
    }
    float* sc = &scratch[g * 272 + lane * 17];
    #pragma unroll
    for (int j = 0; j < OUTC; ++j) sc[j] = p[j];
    __syncthreads();

    // lane L sums column L over the 16 lanes
    float o = 0.f;
    const float* sg = &scratch[g * 272];
    #pragma unroll
    for (int j = 0; j < 16; ++j) o += sg[j * 17 + lane];
    h2[(size_t)n * OUTC + lane] = __float2half(o);

    float ps = o * a_s2[lane], pd = o * a_d2[lane];
    ps += __shfl_xor(ps, 1, 16); pd += __shfl_xor(pd, 1, 16);
    ps += __shfl_xor(ps, 2, 16); pd += __shfl_xor(pd, 2, 16);
    ps += __shfl_xor(ps, 4, 16); pd += __shfl_xor(pd, 4, 16);
    ps += __shfl_xor(ps, 8, 16); pd += __shfl_xor(pd, 8, 16);
    if (lane == 0) { als2[n] = ps; ald2[n] = pd; }
}

// ------ Layer 2 gather: 4 lanes/node, 4 fp16 feats/lane, no-max softmax ----
__global__ __launch_bounds__(256) void agg2_kernel(
    const int* __restrict__ rowstart, const int* __restrict__ csr,
    const __half* __restrict__ h2, const float* __restrict__ als,
    const float* __restrict__ ald, const float* __restrict__ b2,
    float* __restrict__ out)
{
    int tid = threadIdx.x;
    int n = blockIdx.x * 64 + (tid >> 2);
    if (n >= N_NODES) return;
    int c = (tid & 3) * 4;
    float aldn = ald[n];
    float v0 = als[n] + aldn;
    v0 = fmaxf(v0, NEG * v0);
    float w0 = __expf(v0);
    float sum = w0;
    H4 hs; hs.u = *(const ushort4*)(h2 + (size_t)n * OUTC + c);
    float a0 = w0 * __half2float(hs.h[0]), a1 = w0 * __half2float(hs.h[1]);
    float a2 = w0 * __half2float(hs.h[2]), a3 = w0 * __half2float(hs.h[3]);
    int r0 = rowstart[n], r1 = rowstart[n + 1];

    int sB = (r0 + 1 < r1) ? csr[r0 + 1] : 0;
    float vN = 0.f; H4 hN; hN.u = make_ushort4(0, 0, 0, 0);
    if (r0 < r1) {
        int sA = csr[r0];
        float t = als[sA] + aldn;
        vN = fmaxf(t, NEG * t);
        hN.u = *(const ushort4*)(h2 + (size_t)sA * OUTC + c);
    }
    for (int k = r0; k < r1; ++k) {
        float v = vN; H4 hv = hN;
        int sC = (k + 2 < r1) ? csr[k + 2] : 0;
        if (k + 1 < r1) {
            float t = als[sB] + aldn;
            vN = fmaxf(t, NEG * t);
            hN.u = *(const ushort4*)(h2 + (size_t)sB * OUTC + c);
        }
        sB = sC;
        float w = __expf(v);
        sum += w;
        a0 = fmaf(w, __half2float(hv.h[0]), a0);
        a1 = fmaf(w, __half2float(hv.h[1]), a1);
        a2 = fmaf(w, __half2float(hv.h[2]), a2);
        a3 = fmaf(w, __half2float(hv.h[3]), a3);
    }
    float inv = 1.0f / sum;
    float4 bv = *(const float4*)(b2 + c);
    float4 o;
    o.x = a0 * inv + bv.x; o.y = a1 * inv + bv.y;
    o.z = a2 * inv + bv.z; o.w = a3 * inv + bv.w;
    *(float4*)(out + (size_t)n * OUTC + c) = o;
}

extern "C" void kernel_launch(void* const* d_in, const int* in_sizes, int n_in,
                              void* d_out, int out_size, void* d_ws, size_t ws_size,
                              hipStream_t stream)
{
    const float* x   = (const float*)d_in[0];
    const int*   ei  = (const int*)  d_in[1];
    const float* W1  = (const float*)d_in[2];
    const float* as1 = (const float*)d_in[3];
    const float* ad1 = (const float*)d_in[4];
    const float* b1  = (const float*)d_in[5];
    const float* W2  = (const float*)d_in[6];
    const float* as2 = (const float*)d_in[7];
    const float* ad2 = (const float*)d_in[8];
    const float* b2  = (const float*)d_in[9];
    float* out = (float*)d_out;

    char* wsb = (char*)d_ws;
    const size_t SZ_H1 = (size_t)N_NODES * F1 * sizeof(__half);   // 12.8 MB
    __half* h1h = (__half*)wsb;
    float*  als1 = (float*)(wsb + SZ_H1);                         // N*8
    float*  ald1 = als1 + N_NODES * HEADS;                        // N*8
    __half* h2f  = (__half*)(ald1 + N_NODES * HEADS);             // N*16 fp16
    float*  als2 = (float*)(h2f + (size_t)N_NODES * OUTC);        // N
    float*  ald2 = als2 + N_NODES;                                // N
    int2*   tmp  = (int2*)(ald2 + N_NODES);                       // NE int2
    int*    cnt  = (int*)(tmp + NE);                              // NBKT*NPART
    int*    csr  = cnt + NBKT * NPART;                            // NE
    int*    rowstart = csr + NE;                                  // N+1

    // ---- CSR build ----
    part_hist   <<<NPART, 256, 0, stream>>>(ei, cnt);
    scan50k     <<<1, 1024, 0, stream>>>(cnt);
    part_scatter<<<NPART, 256, 0, stream>>>(ei, cnt, tmp);
    bucket_sort <<<NBKT, 256, 0, stream>>>(tmp, cnt, rowstart, csr);

    // ---- layer 1 GEMM ----
    node1_kernel<<<(N_NODES + 63) / 64, 256, 0, stream>>>(x, W1, as1, ad1, h1h, als1, ald1);

    // ---- fused layer-1 gather + layer-2 GEMV ----
    agg1_node2_kernel<<<N_NODES / 16, 256, 0, stream>>>(rowstart, csr, h1h, als1, ald1, b1,
                                                        W2, as2, ad2, h2f, als2, ald2);

    // ---- layer 2 gather ----
    agg2_kernel<<<(N_NODES + 63) / 64, 256, 0, stream>>>(rowstart, csr, h2f, als2, ald2, b2, out);
}

// Round 9
// 291.215 us; speedup vs baseline: 1.0625x; 1.0625x over previous
//
#include <hip/hip_runtime.h>
#include <hip/hip_fp16.h>
#include <math.h>

#define N_NODES 50000
#define NE      800000
#define INC     128
#define F1      128     // HEADS*HID
#define HEADS   8
#define HID     16
#define OUTC    16
#define NEG     0.2f
#define NBKT    196      // (N_NODES+255)>>8
#define NPART   128      // partition blocks

union H4 { ushort4 u; __half h[4]; };
union H8 { uint4 u; __half h[8]; };

typedef _Float16 f16x8 __attribute__((ext_vector_type(8)));
typedef float    f32x4 __attribute__((ext_vector_type(4)));

// ============ CSR build: two-level counting sort (locality-friendly) ========
__global__ __launch_bounds__(256) void part_hist(const int* __restrict__ ei,
                                                 int* __restrict__ cnt) {
    __shared__ int h[NBKT];
    int tid = threadIdx.x;
    for (int i = tid; i < NBKT; i += 256) h[i] = 0;
    __syncthreads();
    for (int e = blockIdx.x * 256 + tid; e < NE; e += NPART * 256)
        atomicAdd(&h[ei[NE + e] >> 8], 1);
    __syncthreads();
    for (int i = tid; i < NBKT; i += 256) cnt[i * NPART + blockIdx.x] = h[i];
}

__global__ __launch_bounds__(1024) void scan25k(int* __restrict__ cnt) {
    __shared__ int part[1024];
    const int TOT = NBKT * NPART;             // 25088
    const int PER = (TOT + 1023) / 1024;      // 25
    int tid = threadIdx.x;
    int base = tid * PER;
    int s = 0;
    for (int i = 0; i < PER; ++i) {
        int idx = base + i;
        if (idx < TOT) s += cnt[idx];
    }
    part[tid] = s; __syncthreads();
    for (int off = 1; off < 1024; off <<= 1) {
        int t = (tid >= off) ? part[tid - off] : 0;
        __syncthreads();
        part[tid] += t;
        __syncthreads();
    }
    int run = part[tid] - s;
    for (int i = 0; i < PER; ++i) {
        int idx = base + i;
        if (idx < TOT) { int v = cnt[idx]; cnt[idx] = run; run += v; }
    }
}

__global__ __launch_bounds__(256) void part_scatter(const int* __restrict__ ei,
                                                    const int* __restrict__ cnt,
                                                    int2* __restrict__ tmp) {
    __shared__ int cur[NBKT];
    int tid = threadIdx.x;
    for (int i = tid; i < NBKT; i += 256) cur[i] = cnt[i * NPART + blockIdx.x];
    __syncthreads();
    for (int e = blockIdx.x * 256 + tid; e < NE; e += NPART * 256) {
        int s = ei[e], d = ei[NE + e];
        int p = atomicAdd(&cur[d >> 8], 1);
        tmp[p] = make_int2(s, d);
    }
}

__global__ __launch_bounds__(256) void bucket_sort(const int2* __restrict__ tmp,
                                                   const int* __restrict__ cnt,
                                                   int* __restrict__ rowstart,
                                                   int* __restrict__ csr) {
    __shared__ int h[256];
    int b = blockIdx.x, tid = threadIdx.x;
    int base = cnt[b * NPART];
    int end  = (b == NBKT - 1) ? NE : cnt[(b + 1) * NPART];
    h[tid] = 0; __syncthreads();
    for (int i = base + tid; i < end; i += 256)
        atomicAdd(&h[tmp[i].y & 255], 1);
    __syncthreads();
    int v = h[tid];
    for (int off = 1; off < 256; off <<= 1) {
        int t = (tid >= off) ? h[tid - off] : 0;
        __syncthreads();
        h[tid] += t;
        __syncthreads();
    }
    int excl = h[tid] - v;
    int n = (b << 8) + tid;
    if (n <= N_NODES) rowstart[n] = base + excl;
    __syncthreads();
    h[tid] = excl;
    __syncthreads();
    for (int i = base + tid; i < end; i += 256) {
        int2 e = tmp[i];
        int p = base + atomicAdd(&h[e.y & 255], 1);
        csr[p] = e.x;
    }
}

// ---------------- Layer 1: MFMA GEMM (x @ W1), fp16 in, f32 acc ------------
__global__ __launch_bounds__(256) void node1_kernel(
    const float* __restrict__ x, const float* __restrict__ W1,
    const float* __restrict__ a_src, const float* __restrict__ a_dst,
    __half* __restrict__ hfeat, float* __restrict__ als, float* __restrict__ ald)
{
    __shared__ _Float16 Xh[64 * 136];    // 17.4 KB
    __shared__ _Float16 Wt[128 * 136];   // 34.8 KB
    int tid = threadIdx.x;
    int n0 = blockIdx.x * 64;

    for (int idx = tid; idx < INC * F1 / 4; idx += 256) {
        int k = idx >> 5, n4 = (idx & 31) * 4;
        float4 w = ((const float4*)W1)[idx];
        Wt[(n4 + 0) * 136 + k] = (_Float16)w.x;
        Wt[(n4 + 1) * 136 + k] = (_Float16)w.y;
        Wt[(n4 + 2) * 136 + k] = (_Float16)w.z;
        Wt[(n4 + 3) * 136 + k] = (_Float16)w.w;
    }
    for (int idx = tid; idx < 64 * 32; idx += 256) {
        int m = idx >> 5, f4 = idx & 31;
        int n = n0 + m;
        float4 v = (n < N_NODES) ? ((const float4*)(x + (size_t)n * INC))[f4]
                                 : make_float4(0.f, 0.f, 0.f, 0.f);
        union { unsigned long long u; _Float16 h[4]; } p;
        p.h[0] = (_Float16)v.x; p.h[1] = (_Float16)v.y;
        p.h[2] = (_Float16)v.z; p.h[3] = (_Float16)v.w;
        *(unsigned long long*)(&Xh[m * 136 + f4 * 4]) = p.u;
    }
    __syncthreads();

    int wave = tid >> 6, lane = tid & 63;
    int colL = lane & 15, q = lane >> 4;
    int nb = wave * 32;

    f32x4 acc[4][2];
    #pragma unroll
    for (int mt = 0; mt < 4; ++mt)
        #pragma unroll
        for (int nt = 0; nt < 2; ++nt)
            acc[mt][nt] = (f32x4){0.f, 0.f, 0.f, 0.f};

    #pragma unroll
    for (int kb = 0; kb < 4; ++kb) {
        int ko = kb * 32 + q * 8;
        f16x8 b0 = *(const f16x8*)(&Wt[(nb +  0 + colL) * 136 + ko]);
        f16x8 b1 = *(const f16x8*)(&Wt[(nb + 16 + colL) * 136 + ko]);
        #pragma unroll
        for (int mt = 0; mt < 4; ++mt) {
            f16x8 a = *(const f16x8*)(&Xh[(mt * 16 + colL) * 136 + ko]);
            acc[mt][0] = __builtin_amdgcn_mfma_f32_16x16x32_f16(a, b0, acc[mt][0], 0, 0, 0);
            acc[mt][1] = __builtin_amdgcn_mfma_f32_16x16x32_f16(a, b1, acc[mt][1], 0, 0, 0);
        }
    }

    #pragma unroll
    for (int nt = 0; nt < 2; ++nt) {
        int col = nb + nt * 16 + colL;
        int head = (nb >> 4) + nt;
        float asc = a_src[col], adc = a_dst[col];
        #pragma unroll
        for (int mt = 0; mt < 4; ++mt) {
            f32x4 d = acc[mt][nt];
            #pragma unroll
            for (int r = 0; r < 4; ++r) {
                int node = n0 + mt * 16 + q * 4 + r;
                float dv = d[r];
                if (node < N_NODES) hfeat[(size_t)node * F1 + col] = __float2half(dv);
                float ps = dv * asc, pd = dv * adc;
                ps += __shfl_xor(ps, 1, 16); pd += __shfl_xor(pd, 1, 16);
                ps += __shfl_xor(ps, 2, 16); pd += __shfl_xor(pd, 2, 16);
                ps += __shfl_xor(ps, 4, 16); pd += __shfl_xor(pd, 4, 16);
                ps += __shfl_xor(ps, 8, 16); pd += __shfl_xor(pd, 8, 16);
                if (colL == 0 && node < N_NODES) {
                    als[node * HEADS + head] = ps;
                    ald[node * HEADS + head] = pd;
                }
            }
        }
    }
}

// ------ Layer 1 gather: 16 lanes/node, 8 fp16/lane, depth-2 row pipeline ---
__global__ __launch_bounds__(256) void agg1_kernel(
    const int* __restrict__ rowstart, const int* __restrict__ csr,
    const __half* __restrict__ h1, const float* __restrict__ als,
    const float* __restrict__ ald, const float* __restrict__ b1,
    __half* __restrict__ hout)
{
    int tid = threadIdx.x;
    int n = blockIdx.x * 16 + (tid >> 4);
    int lane = tid & 15;
    int c = lane * 8;
    int head = lane >> 1;
    float aldn = ald[n * HEADS + head];
    float v0 = als[n * HEADS + head] + aldn;
    v0 = fmaxf(v0, NEG * v0);
    float w0 = __expf(v0);
    float sum = w0;
    float a[8];
    {
        H8 hs; hs.u = *(const uint4*)(h1 + (size_t)n * F1 + c);
        #pragma unroll
        for (int i = 0; i < 8; ++i) a[i] = w0 * __half2float(hs.h[i]);
    }
    int r0 = rowstart[n], r1 = rowstart[n + 1];

    // depth-2: rows for k, k+1 in flight; csr indices prefetched 4 ahead
    int sP0 = (r0 + 2 < r1) ? csr[r0 + 2] : 0;
    int sP1 = (r0 + 3 < r1) ? csr[r0 + 3] : 0;
    float vb[2]; H8 hb[2];
    #pragma unroll
    for (int j = 0; j < 2; ++j) {
        vb[j] = 0.f; hb[j].u = make_uint4(0, 0, 0, 0);
        if (r0 + j < r1) {
            int s = csr[r0 + j];
            float t = als[s * HEADS + head] + aldn;
            vb[j] = fmaxf(t, NEG * t);
            hb[j].u = *(const uint4*)(h1 + (size_t)s * F1 + c);
        }
    }
    for (int k = r0; k < r1; ++k) {
        int i = (k - r0) & 1;
        float v = vb[i]; H8 hv = hb[i];
        int sn = sP0; sP0 = sP1; sP1 = (k + 4 < r1) ? csr[k + 4] : 0;
        if (k + 2 < r1) {
            float t = als[sn * HEADS + head] + aldn;
            vb[i] = fmaxf(t, NEG * t);
            hb[i].u = *(const uint4*)(h1 + (size_t)sn * F1 + c);
        }
        float w = __expf(v);
        sum += w;
        #pragma unroll
        for (int i8 = 0; i8 < 8; ++i8) a[i8] = fmaf(w, __half2float(hv.h[i8]), a[i8]);
    }
    float inv = 1.0f / sum;
    H8 t;
    #pragma unroll
    for (int i = 0; i < 8; ++i) {
        float o = a[i] * inv + b1[c + i];
        o = o > 0.f ? o : (__expf(o) - 1.0f);
        t.h[i] = __float2half(o);
    }
    *(uint4*)(hout + (size_t)n * F1 + c) = t.u;
}

// ---------------- Layer 2: GEMM (h1' @ W2) + logits, fp16 in/out ----------
__global__ __launch_bounds__(256) void node2_kernel(
    const __half* __restrict__ h1, const float* __restrict__ W2,
    const float* __restrict__ a_s, const float* __restrict__ a_d,
    __half* __restrict__ h2, float* __restrict__ als2, float* __restrict__ ald2)
{
    __shared__ float W2l[F1 * OUTC];   // 8 KB
    for (int i = threadIdx.x; i < F1 * OUTC; i += 256) W2l[i] = W2[i];
    __syncthreads();
    int n = blockIdx.x * blockDim.x + threadIdx.x;
    if (n >= N_NODES) return;

    float o[OUTC];
    #pragma unroll
    for (int c = 0; c < OUTC; ++c) o[c] = 0.f;
    const uint4* xr = (const uint4*)(h1 + (size_t)n * F1);
    for (int k8 = 0; k8 < 16; ++k8) {
        H8 xv; xv.u = xr[k8];
        int k = k8 * 8;
        #pragma unroll
        for (int j = 0; j < 8; ++j) {
            float xf = __half2float(xv.h[j]);
            #pragma unroll
            for (int c = 0; c < OUTC; ++c)
                o[c] = fmaf(xf, W2l[(k + j) * OUTC + c], o[c]);
        }
    }
    H8 s0, s1;
    #pragma unroll
    for (int j = 0; j < 8; ++j) { s0.h[j] = __float2half(o[j]); s1.h[j] = __float2half(o[8 + j]); }
    uint4* h2o = (uint4*)(h2 + (size_t)n * OUTC);
    h2o[0] = s0.u; h2o[1] = s1.u;
    float ps = 0.f, pd = 0.f;
    #pragma unroll
    for (int c = 0; c < OUTC; ++c) { ps += o[c] * a_s[c]; pd += o[c] * a_d[c]; }
    als2[n] = ps; ald2[n] = pd;
}

// ------ Layer 2 gather: 4 lanes/node, 4 fp16/lane, depth-2 pipeline --------
__global__ __launch_bounds__(256) void agg2_kernel(
    const int* __restrict__ rowstart, const int* __restrict__ csr,
    const __half* __restrict__ h2, const float* __restrict__ als,
    const float* __restrict__ ald, const float* __restrict__ b2,
    float* __restrict__ out)
{
    int tid = threadIdx.x;
    int n = blockIdx.x * 64 + (tid >> 2);
    if (n >= N_NODES) return;
    int c = (tid & 3) * 4;
    float aldn = ald[n];
    float v0 = als[n] + aldn;
    v0 = fmaxf(v0, NEG * v0);
    float w0 = __expf(v0);
    float sum = w0;
    H4 hs; hs.u = *(const ushort4*)(h2 + (size_t)n * OUTC + c);
    float a0 = w0 * __half2float(hs.h[0]), a1 = w0 * __half2float(hs.h[1]);
    float a2 = w0 * __half2float(hs.h[2]), a3 = w0 * __half2float(hs.h[3]);
    int r0 = rowstart[n], r1 = rowstart[n + 1];

    int sP0 = (r0 + 2 < r1) ? csr[r0 + 2] : 0;
    int sP1 = (r0 + 3 < r1) ? csr[r0 + 3] : 0;
    float vb[2]; H4 hb[2];
    #pragma unroll
    for (int j = 0; j < 2; ++j) {
        vb[j] = 0.f; hb[j].u = make_ushort4(0, 0, 0, 0);
        if (r0 + j < r1) {
            int s = csr[r0 + j];
            float t = als[s] + aldn;
            vb[j] = fmaxf(t, NEG * t);
            hb[j].u = *(const ushort4*)(h2 + (size_t)s * OUTC + c);
        }
    }
    for (int k = r0; k < r1; ++k) {
        int i = (k - r0) & 1;
        float v = vb[i]; H4 hv = hb[i];
        int sn = sP0; sP0 = sP1; sP1 = (k + 4 < r1) ? csr[k + 4] : 0;
        if (k + 2 < r1) {
            float t = als[sn] + aldn;
            vb[i] = fmaxf(t, NEG * t);
            hb[i].u = *(const ushort4*)(h2 + (size_t)sn * OUTC + c);
        }
        float w = __expf(v);
        sum += w;
        a0 = fmaf(w, __half2float(hv.h[0]), a0);
        a1 = fmaf(w, __half2float(hv.h[1]), a1);
        a2 = fmaf(w, __half2float(hv.h[2]), a2);
        a3 = fmaf(w, __half2float(hv.h[3]), a3);
    }
    float inv = 1.0f / sum;
    float4 bv = *(const float4*)(b2 + c);
    float4 o;
    o.x = a0 * inv + bv.x; o.y = a1 * inv + bv.y;
    o.z = a2 * inv + bv.z; o.w = a3 * inv + bv.w;
    *(float4*)(out + (size_t)n * OUTC + c) = o;
}

extern "C" void kernel_launch(void* const* d_in, const int* in_sizes, int n_in,
                              void* d_out, int out_size, void* d_ws, size_t ws_size,
                              hipStream_t stream)
{
    const float* x   = (const float*)d_in[0];
    const int*   ei  = (const int*)  d_in[1];
    const float* W1  = (const float*)d_in[2];
    const float* as1 = (const float*)d_in[3];
    const float* ad1 = (const float*)d_in[4];
    const float* b1  = (const float*)d_in[5];
    const float* W2  = (const float*)d_in[6];
    const float* as2 = (const float*)d_in[7];
    const float* ad2 = (const float*)d_in[8];
    const float* b2  = (const float*)d_in[9];
    float* out = (float*)d_out;

    char* wsb = (char*)d_ws;
    const size_t SZ_H1 = (size_t)N_NODES * F1 * sizeof(__half);   // 12.8 MB
    __half* h1h = (__half*)wsb;
    __half* h1b = (__half*)(wsb + SZ_H1);
    float*  als1 = (float*)(wsb + 2 * SZ_H1);                     // N*8
    float*  ald1 = als1 + N_NODES * HEADS;                        // N*8
    __half* h2f  = (__half*)(ald1 + N_NODES * HEADS);             // N*16 fp16
    float*  als2 = (float*)(h2f + (size_t)N_NODES * OUTC);        // N
    float*  ald2 = als2 + N_NODES;                                // N
    int2*   tmp  = (int2*)(ald2 + N_NODES);                       // NE int2
    int*    cnt  = (int*)(tmp + NE);                              // NBKT*NPART
    int*    csr  = cnt + NBKT * NPART;                            // NE
    int*    rowstart = csr + NE;                                  // N+1

    // ---- CSR build ----
    part_hist   <<<NPART, 256, 0, stream>>>(ei, cnt);
    scan25k     <<<1, 1024, 0, stream>>>(cnt);
    part_scatter<<<NPART, 256, 0, stream>>>(ei, cnt, tmp);
    bucket_sort <<<NBKT, 256, 0, stream>>>(tmp, cnt, rowstart, csr);

    // ---- layer 1 ----
    node1_kernel<<<(N_NODES + 63) / 64, 256, 0, stream>>>(x, W1, as1, ad1, h1h, als1, ald1);
    agg1_kernel<<<N_NODES / 16, 256, 0, stream>>>(rowstart, csr, h1h, als1, ald1, b1, h1b);

    // ---- layer 2 ----
    node2_kernel<<<(N_NODES + 255) / 256, 256, 0, stream>>>(h1b, W2, as2, ad2, h2f, als2, ald2);
    agg2_kernel<<<(N_NODES + 63) / 64, 256, 0, stream>>>(rowstart, csr, h2f, als2, ald2, b2, out);
}

// Round 10
// 252.036 us; speedup vs baseline: 1.2276x; 1.1555x over previous
//
#include <hip/hip_runtime.h>
#include <hip/hip_fp16.h>
#include <math.h>

#define N_NODES 50000
#define NE      800000
#define INC     128
#define F1      128     // HEADS*HID
#define HEADS   8
#define HID     16
#define OUTC    16
#define NEG     0.2f
#define NBKT    196      // (N_NODES+255)>>8
#define NPART   128      // partition blocks

union H4 { ushort4 u; __half h[4]; };
union H8 { uint4 u; __half h[8]; };

typedef _Float16 f16x8 __attribute__((ext_vector_type(8)));
typedef float    f32x4 __attribute__((ext_vector_type(4)));

// ============ CSR build: two-level counting sort (locality-friendly) ========
__global__ __launch_bounds__(256) void part_hist(const int* __restrict__ ei,
                                                 int* __restrict__ cnt) {
    __shared__ int h[NBKT];
    int tid = threadIdx.x;
    for (int i = tid; i < NBKT; i += 256) h[i] = 0;
    __syncthreads();
    for (int e = blockIdx.x * 256 + tid; e < NE; e += NPART * 256)
        atomicAdd(&h[ei[NE + e] >> 8], 1);
    __syncthreads();
    for (int i = tid; i < NBKT; i += 256) cnt[i * NPART + blockIdx.x] = h[i];
}

__global__ __launch_bounds__(1024) void scan25k(int* __restrict__ cnt) {
    __shared__ int part[1024];
    const int TOT = NBKT * NPART;             // 25088
    const int PER = (TOT + 1023) / 1024;      // 25
    int tid = threadIdx.x;
    int base = tid * PER;
    int s = 0;
    for (int i = 0; i < PER; ++i) {
        int idx = base + i;
        if (idx < TOT) s += cnt[idx];
    }
    part[tid] = s; __syncthreads();
    for (int off = 1; off < 1024; off <<= 1) {
        int t = (tid >= off) ? part[tid - off] : 0;
        __syncthreads();
        part[tid] += t;
        __syncthreads();
    }
    int run = part[tid] - s;
    for (int i = 0; i < PER; ++i) {
        int idx = base + i;
        if (idx < TOT) { int v = cnt[idx]; cnt[idx] = run; run += v; }
    }
}

__global__ __launch_bounds__(256) void part_scatter(const int* __restrict__ ei,
                                                    const int* __restrict__ cnt,
                                                    int2* __restrict__ tmp) {
    __shared__ int cur[NBKT];
    int tid = threadIdx.x;
    for (int i = tid; i < NBKT; i += 256) cur[i] = cnt[i * NPART + blockIdx.x];
    __syncthreads();
    for (int e = blockIdx.x * 256 + tid; e < NE; e += NPART * 256) {
        int s = ei[e], d = ei[NE + e];
        int p = atomicAdd(&cur[d >> 8], 1);
        tmp[p] = make_int2(s, d);
    }
}

__global__ __launch_bounds__(256) void bucket_sort(const int2* __restrict__ tmp,
                                                   const int* __restrict__ cnt,
                                                   int* __restrict__ rowstart,
                                                   int* __restrict__ csr) {
    __shared__ int h[256];
    int b = blockIdx.x, tid = threadIdx.x;
    int base = cnt[b * NPART];
    int end  = (b == NBKT - 1) ? NE : cnt[(b + 1) * NPART];
    h[tid] = 0; __syncthreads();
    for (int i = base + tid; i < end; i += 256)
        atomicAdd(&h[tmp[i].y & 255], 1);
    __syncthreads();
    int v = h[tid];
    for (int off = 1; off < 256; off <<= 1) {
        int t = (tid >= off) ? h[tid - off] : 0;
        __syncthreads();
        h[tid] += t;
        __syncthreads();
    }
    int excl = h[tid] - v;
    int n = (b << 8) + tid;
    if (n <= N_NODES) rowstart[n] = base + excl;
    __syncthreads();
    h[tid] = excl;
    __syncthreads();
    for (int i = base + tid; i < end; i += 256) {
        int2 e = tmp[i];
        int p = base + atomicAdd(&h[e.y & 255], 1);
        csr[p] = e.x;
    }
}

// ---------------- Layer 1: MFMA GEMM (x @ W1), fp16 in, f32 acc ------------
__global__ __launch_bounds__(256) void node1_kernel(
    const float* __restrict__ x, const float* __restrict__ W1,
    const float* __restrict__ a_src, const float* __restrict__ a_dst,
    __half* __restrict__ hfeat, float* __restrict__ als, float* __restrict__ ald)
{
    __shared__ _Float16 Xh[64 * 136];    // 17.4 KB
    __shared__ _Float16 Wt[128 * 136];   // 34.8 KB
    int tid = threadIdx.x;
    int n0 = blockIdx.x * 64;

    for (int idx = tid; idx < INC * F1 / 4; idx += 256) {
        int k = idx >> 5, n4 = (idx & 31) * 4;
        float4 w = ((const float4*)W1)[idx];
        Wt[(n4 + 0) * 136 + k] = (_Float16)w.x;
        Wt[(n4 + 1) * 136 + k] = (_Float16)w.y;
        Wt[(n4 + 2) * 136 + k] = (_Float16)w.z;
        Wt[(n4 + 3) * 136 + k] = (_Float16)w.w;
    }
    for (int idx = tid; idx < 64 * 32; idx += 256) {
        int m = idx >> 5, f4 = idx & 31;
        int n = n0 + m;
        float4 v = (n < N_NODES) ? ((const float4*)(x + (size_t)n * INC))[f4]
                                 : make_float4(0.f, 0.f, 0.f, 0.f);
        union { unsigned long long u; _Float16 h[4]; } p;
        p.h[0] = (_Float16)v.x; p.h[1] = (_Float16)v.y;
        p.h[2] = (_Float16)v.z; p.h[3] = (_Float16)v.w;
        *(unsigned long long*)(&Xh[m * 136 + f4 * 4]) = p.u;
    }
    __syncthreads();

    int wave = tid >> 6, lane = tid & 63;
    int colL = lane & 15, q = lane >> 4;
    int nb = wave * 32;

    f32x4 acc[4][2];
    #pragma unroll
    for (int mt = 0; mt < 4; ++mt)
        #pragma unroll
        for (int nt = 0; nt < 2; ++nt)
            acc[mt][nt] = (f32x4){0.f, 0.f, 0.f, 0.f};

    #pragma unroll
    for (int kb = 0; kb < 4; ++kb) {
        int ko = kb * 32 + q * 8;
        f16x8 b0 = *(const f16x8*)(&Wt[(nb +  0 + colL) * 136 + ko]);
        f16x8 b1 = *(const f16x8*)(&Wt[(nb + 16 + colL) * 136 + ko]);
        #pragma unroll
        for (int mt = 0; mt < 4; ++mt) {
            f16x8 a = *(const f16x8*)(&Xh[(mt * 16 + colL) * 136 + ko]);
            acc[mt][0] = __builtin_amdgcn_mfma_f32_16x16x32_f16(a, b0, acc[mt][0], 0, 0, 0);
            acc[mt][1] = __builtin_amdgcn_mfma_f32_16x16x32_f16(a, b1, acc[mt][1], 0, 0, 0);
        }
    }

    #pragma unroll
    for (int nt = 0; nt < 2; ++nt) {
        int col = nb + nt * 16 + colL;
        int head = (nb >> 4) + nt;
        float asc = a_src[col], adc = a_dst[col];
        #pragma unroll
        for (int mt = 0; mt < 4; ++mt) {
            f32x4 d = acc[mt][nt];
            #pragma unroll
            for (int r = 0; r < 4; ++r) {
                int node = n0 + mt * 16 + q * 4 + r;
                float dv = d[r];
                if (node < N_NODES) hfeat[(size_t)node * F1 + col] = __float2half(dv);
                float ps = dv * asc, pd = dv * adc;
                ps += __shfl_xor(ps, 1, 16); pd += __shfl_xor(pd, 1, 16);
                ps += __shfl_xor(ps, 2, 16); pd += __shfl_xor(pd, 2, 16);
                ps += __shfl_xor(ps, 4, 16); pd += __shfl_xor(pd, 4, 16);
                ps += __shfl_xor(ps, 8, 16); pd += __shfl_xor(pd, 8, 16);
                if (colL == 0 && node < N_NODES) {
                    als[node * HEADS + head] = ps;
                    ald[node * HEADS + head] = pd;
                }
            }
        }
    }
}

// ------ Layer 1 gather: 16 lanes/node, 8 fp16/lane, depth-2 STATIC pipeline -
// (R9 lesson: rotating buffers with dynamic index get demoted to LDS scratch;
//  named slots A/B keep everything in VGPRs.)
__global__ __launch_bounds__(256) void agg1_kernel(
    const int* __restrict__ rowstart, const int* __restrict__ csr,
    const __half* __restrict__ h1, const float* __restrict__ als,
    const float* __restrict__ ald, const float* __restrict__ b1,
    __half* __restrict__ hout)
{
    int tid = threadIdx.x;
    int n = blockIdx.x * 16 + (tid >> 4);
    int lane = tid & 15;
    int c = lane * 8;
    int head = lane >> 1;
    float aldn = ald[n * HEADS + head];
    float v0 = als[n * HEADS + head] + aldn;
    v0 = fmaxf(v0, NEG * v0);
    float w0 = __expf(v0);
    float sum = w0;
    float a[8];
    {
        H8 hs; hs.u = *(const uint4*)(h1 + (size_t)n * F1 + c);
        #pragma unroll
        for (int i = 0; i < 8; ++i) a[i] = w0 * __half2float(hs.h[i]);
    }
    int r0 = rowstart[n], r1 = rowstart[n + 1];

    // named slots: A=edge k, B=edge k+1 in flight; sC/sD = indices k+2,k+3
    float vA = 0.f, vB = 0.f;
    H8 hA, hB; hA.u = make_uint4(0,0,0,0); hB.u = hA.u;
    int sC = 0, sD = 0;
    if (r0 < r1) {
        int s = csr[r0];
        float t = als[s * HEADS + head] + aldn;
        vA = fmaxf(t, NEG * t);
        hA.u = *(const uint4*)(h1 + (size_t)s * F1 + c);
    }
    if (r0 + 1 < r1) {
        int s = csr[r0 + 1];
        float t = als[s * HEADS + head] + aldn;
        vB = fmaxf(t, NEG * t);
        hB.u = *(const uint4*)(h1 + (size_t)s * F1 + c);
    }
    if (r0 + 2 < r1) sC = csr[r0 + 2];
    if (r0 + 3 < r1) sD = csr[r0 + 3];

    int k = r0;
    for (; k + 1 < r1; k += 2) {
        float vcA = vA, vcB = vB;
        H8 hcA = hA, hcB = hB;
        int sE = (k + 4 < r1) ? csr[k + 4] : 0;
        int sF = (k + 5 < r1) ? csr[k + 5] : 0;
        if (k + 2 < r1) {
            float t = als[sC * HEADS + head] + aldn;
            vA = fmaxf(t, NEG * t);
            hA.u = *(const uint4*)(h1 + (size_t)sC * F1 + c);
        }
        if (k + 3 < r1) {
            float t = als[sD * HEADS + head] + aldn;
            vB = fmaxf(t, NEG * t);
            hB.u = *(const uint4*)(h1 + (size_t)sD * F1 + c);
        }
        sC = sE; sD = sF;
        float wA = __expf(vcA), wB = __expf(vcB);
        sum += wA + wB;
        #pragma unroll
        for (int i = 0; i < 8; ++i) {
            a[i] = fmaf(wA, __half2float(hcA.h[i]), a[i]);
            a[i] = fmaf(wB, __half2float(hcB.h[i]), a[i]);
        }
    }
    if (k < r1) {                      // odd tail: consume slot A
        float wA = __expf(vA);
        sum += wA;
        #pragma unroll
        for (int i = 0; i < 8; ++i) a[i] = fmaf(wA, __half2float(hA.h[i]), a[i]);
    }

    float inv = 1.0f / sum;
    H8 t;
    #pragma unroll
    for (int i = 0; i < 8; ++i) {
        float o = a[i] * inv + b1[c + i];
        o = o > 0.f ? o : (__expf(o) - 1.0f);
        t.h[i] = __float2half(o);
    }
    *(uint4*)(hout + (size_t)n * F1 + c) = t.u;
}

// ---------------- Layer 2: GEMM (h1' @ W2) + logits, fp16 in/out ----------
__global__ __launch_bounds__(256) void node2_kernel(
    const __half* __restrict__ h1, const float* __restrict__ W2,
    const float* __restrict__ a_s, const float* __restrict__ a_d,
    __half* __restrict__ h2, float* __restrict__ als2, float* __restrict__ ald2)
{
    __shared__ float W2l[F1 * OUTC];   // 8 KB
    for (int i = threadIdx.x; i < F1 * OUTC; i += 256) W2l[i] = W2[i];
    __syncthreads();
    int n = blockIdx.x * blockDim.x + threadIdx.x;
    if (n >= N_NODES) return;

    float o[OUTC];
    #pragma unroll
    for (int c = 0; c < OUTC; ++c) o[c] = 0.f;
    const uint4* xr = (const uint4*)(h1 + (size_t)n * F1);
    for (int k8 = 0; k8 < 16; ++k8) {
        H8 xv; xv.u = xr[k8];
        int k = k8 * 8;
        #pragma unroll
        for (int j = 0; j < 8; ++j) {
            float xf = __half2float(xv.h[j]);
            #pragma unroll
            for (int c = 0; c < OUTC; ++c)
                o[c] = fmaf(xf, W2l[(k + j) * OUTC + c], o[c]);
        }
    }
    H8 s0, s1;
    #pragma unroll
    for (int j = 0; j < 8; ++j) { s0.h[j] = __float2half(o[j]); s1.h[j] = __float2half(o[8 + j]); }
    uint4* h2o = (uint4*)(h2 + (size_t)n * OUTC);
    h2o[0] = s0.u; h2o[1] = s1.u;
    float ps = 0.f, pd = 0.f;
    #pragma unroll
    for (int c = 0; c < OUTC; ++c) { ps += o[c] * a_s[c]; pd += o[c] * a_d[c]; }
    als2[n] = ps; ald2[n] = pd;
}

// ------ Layer 2 gather: 4 lanes/node, 4 fp16/lane, depth-2 STATIC pipeline -
__global__ __launch_bounds__(256) void agg2_kernel(
    const int* __restrict__ rowstart, const int* __restrict__ csr,
    const __half* __restrict__ h2, const float* __restrict__ als,
    const float* __restrict__ ald, const float* __restrict__ b2,
    float* __restrict__ out)
{
    int tid = threadIdx.x;
    int n = blockIdx.x * 64 + (tid >> 2);
    if (n >= N_NODES) return;
    int c = (tid & 3) * 4;
    float aldn = ald[n];
    float v0 = als[n] + aldn;
    v0 = fmaxf(v0, NEG * v0);
    float w0 = __expf(v0);
    float sum = w0;
    H4 hs; hs.u = *(const ushort4*)(h2 + (size_t)n * OUTC + c);
    float a0 = w0 * __half2float(hs.h[0]), a1 = w0 * __half2float(hs.h[1]);
    float a2 = w0 * __half2float(hs.h[2]), a3 = w0 * __half2float(hs.h[3]);
    int r0 = rowstart[n], r1 = rowstart[n + 1];

    float vA = 0.f, vB = 0.f;
    H4 hA, hB; hA.u = make_ushort4(0,0,0,0); hB.u = hA.u;
    int sC = 0, sD = 0;
    if (r0 < r1) {
        int s = csr[r0];
        float t = als[s] + aldn;
        vA = fmaxf(t, NEG * t);
        hA.u = *(const ushort4*)(h2 + (size_t)s * OUTC + c);
    }
    if (r0 + 1 < r1) {
        int s = csr[r0 + 1];
        float t = als[s] + aldn;
        vB = fmaxf(t, NEG * t);
        hB.u = *(const ushort4*)(h2 + (size_t)s * OUTC + c);
    }
    if (r0 + 2 < r1) sC = csr[r0 + 2];
    if (r0 + 3 < r1) sD = csr[r0 + 3];

    int k = r0;
    for (; k + 1 < r1; k += 2) {
        float vcA = vA, vcB = vB;
        H4 hcA = hA, hcB = hB;
        int sE = (k + 4 < r1) ? csr[k + 4] : 0;
        int sF = (k + 5 < r1) ? csr[k + 5] : 0;
        if (k + 2 < r1) {
            float t = als[sC] + aldn;
            vA = fmaxf(t, NEG * t);
            hA.u = *(const ushort4*)(h2 + (size_t)sC * OUTC + c);
        }
        if (k + 3 < r1) {
            float t = als[sD] + aldn;
            vB = fmaxf(t, NEG * t);
            hB.u = *(const ushort4*)(h2 + (size_t)sD * OUTC + c);
        }
        sC = sE; sD = sF;
        float wA = __expf(vcA), wB = __expf(vcB);
        sum += wA + wB;
        a0 = fmaf(wA, __half2float(hcA.h[0]), a0); a0 = fmaf(wB, __half2float(hcB.h[0]), a0);
        a1 = fmaf(wA, __half2float(hcA.h[1]), a1); a1 = fmaf(wB, __half2float(hcB.h[1]), a1);
        a2 = fmaf(wA, __half2float(hcA.h[2]), a2); a2 = fmaf(wB, __half2float(hcB.h[2]), a2);
        a3 = fmaf(wA, __half2float(hcA.h[3]), a3); a3 = fmaf(wB, __half2float(hcB.h[3]), a3);
    }
    if (k < r1) {
        float wA = __expf(vA);
        sum += wA;
        a0 = fmaf(wA, __half2float(hA.h[0]), a0);
        a1 = fmaf(wA, __half2float(hA.h[1]), a1);
        a2 = fmaf(wA, __half2float(hA.h[2]), a2);
        a3 = fmaf(wA, __half2float(hA.h[3]), a3);
    }

    float inv = 1.0f / sum;
    float4 bv = *(const float4*)(b2 + c);
    float4 o;
    o.x = a0 * inv + bv.x; o.y = a1 * inv + bv.y;
    o.z = a2 * inv + bv.z; o.w = a3 * inv + bv.w;
    *(float4*)(out + (size_t)n * OUTC + c) = o;
}

extern "C" void kernel_launch(void* const* d_in, const int* in_sizes, int n_in,
                              void* d_out, int out_size, void* d_ws, size_t ws_size,
                              hipStream_t stream)
{
    const float* x   = (const float*)d_in[0];
    const int*   ei  = (const int*)  d_in[1];
    const float* W1  = (const float*)d_in[2];
    const float* as1 = (const float*)d_in[3];
    const float* ad1 = (const float*)d_in[4];
    const float* b1  = (const float*)d_in[5];
    const float* W2  = (const float*)d_in[6];
    const float* as2 = (const float*)d_in[7];
    const float* ad2 = (const float*)d_in[8];
    const float* b2  = (const float*)d_in[9];
    float* out = (float*)d_out;

    char* wsb = (char*)d_ws;
    const size_t SZ_H1 = (size_t)N_NODES * F1 * sizeof(__half);   // 12.8 MB
    __half* h1h = (__half*)wsb;
    __half* h1b = (__half*)(wsb + SZ_H1);
    float*  als1 = (float*)(wsb + 2 * SZ_H1);                     // N*8
    float*  ald1 = als1 + N_NODES * HEADS;                        // N*8
    __half* h2f  = (__half*)(ald1 + N_NODES * HEADS);             // N*16 fp16
    float*  als2 = (float*)(h2f + (size_t)N_NODES * OUTC);        // N
    float*  ald2 = als2 + N_NODES;                                // N
    int2*   tmp  = (int2*)(ald2 + N_NODES);                       // NE int2
    int*    cnt  = (int*)(tmp + NE);                              // NBKT*NPART
    int*    csr  = cnt + NBKT * NPART;                            // NE
    int*    rowstart = csr + NE;                                  // N+1

    // ---- CSR build ----
    part_hist   <<<NPART, 256, 0, stream>>>(ei, cnt);
    scan25k     <<<1, 1024, 0, stream>>>(cnt);
    part_scatter<<<NPART, 256, 0, stream>>>(ei, cnt, tmp);
    bucket_sort <<<NBKT, 256, 0, stream>>>(tmp, cnt, rowstart, csr);

    // ---- layer 1 ----
    node1_kernel<<<(N_NODES + 63) / 64, 256, 0, stream>>>(x, W1, as1, ad1, h1h, als1, ald1);
    agg1_kernel<<<N_NODES / 16, 256, 0, stream>>>(rowstart, csr, h1h, als1, ald1, b1, h1b);

    // ---- layer 2 ----
    node2_kernel<<<(N_NODES + 255) / 256, 256, 0, stream>>>(h1b, W2, as2, ad2, h2f, als2, ald2);
    agg2_kernel<<<(N_NODES + 63) / 64, 256, 0, stream>>>(rowstart, csr, h2f, als2, ald2, b2, out);
}